// Round 1
// 337.522 us; speedup vs baseline: 2.6902x; 2.6902x over previous
//
#include <hip/hip_runtime.h>

// VQ-VAE EMA vector quantizer, fp32 in/out.
// N=65536 rows (32*2048), D=256, K=1024 codes.
//
// R8: the distance GEMM (34.4 GFLOP) moves from the fp32 VALU (42 TF achieved,
//     157 TF ceiling) to the matrix cores via a double-f16 split:
//       128*z = zh + zl,  128*e = eh + el   (f16; scale 2^7 keeps residues
//       normal in f16, so no denorm-flush risk inside MFMA)
//       acc = zh*eh + zh*el + zl*eh  (3x mfma_f32_16x16x32_f16, fp32 acc)
//     error ~3e-7 per dot -- BELOW the fp32 reassociation noise (~5e-7) the
//     previous passing kernel already carries, and far below the ~1.5e-5 ulp
//     quantization of (z_sq - 2g) + e_sq that collapses near-ties identically.
//     Descale by 2^-14 is exact (power of two): the fold
//       d = fmaf(acc, -0x1p-13f, zsq) + esq
//     has bit-identical rounding structure to the reference association.
//     Staging: global_load_lds (16B) with XOR chunk swizzle (c ^= row&7)
//     applied on the per-lane GLOBAL source address; LDS dest stays linear.
//     Falls back to the R7 fp32 kernel if ws_size can't hold the f16 copies.

#define DDIM 256
#define DQ   64      // DDIM/4
#define KC   1024
#define NROW 65536
#define BM   128     // rows per block
#define BN   128     // codes per k-tile
#define BD   32      // d-chunk (one K=32 MFMA step per stage)
#define LS   34      // fp32-fallback LDS row stride
#define DECAYF 0.99f
#define OMDF   0.01f
#define BETAF  0.25f
#define EPSF   1e-5f

typedef _Float16 f16;
typedef _Float16 f16x8 __attribute__((ext_vector_type(8)));
typedef float    f32x4 __attribute__((ext_vector_type(4)));

__device__ __forceinline__ void gl_lds16(const f16* g, f16* l) {
    __builtin_amdgcn_global_load_lds(
        (const __attribute__((address_space(1))) void*)g,
        (__attribute__((address_space(3))) void*)l, 16, 0, 0);
}

// one-shot ||e||^2 for all codes (unchanged; feeds the exact-f32 fold)
__global__ __launch_bounds__(256) void vq_esq(const float* __restrict__ emb,
                                              float* __restrict__ esq_g)
{
    int k = blockIdx.x * 256 + threadIdx.x;
    const float4* ep = (const float4*)(emb + (size_t)k * DDIM);
    float s = 0.f;
    for (int q = 0; q < DQ; ++q) {
        float4 v = ep[q];
        s += v.x * v.x + v.y * v.y + v.z * v.z + v.w * v.w;
    }
    esq_g[k] = s;
}

// f32 -> double-f16 split, row layout [row][dc(8)][32 h | 32 l] f16 (512/row).
// h = f16(128*x); l = f16(128*x - h). Exact Sterbenz subtract, RNE converts.
__global__ __launch_bounds__(256) void vq_prep(const float* __restrict__ src,
                                               f16* __restrict__ dst)
{
    int t   = blockIdx.x * 256 + threadIdx.x;   // 8-elem chunk id
    int row = t >> 5;                           // 32 chunks per row
    int c   = t & 31;
    int dc  = c >> 2, q = c & 3;                // dc 0..7 (32-d), q 0..3
    const float4* sp = (const float4*)(src + (size_t)row * DDIM + c * 8);
    float4 v0 = sp[0], v1 = sp[1];
    float x[8] = {v0.x, v0.y, v0.z, v0.w, v1.x, v1.y, v1.z, v1.w};
    f16x8 h, l;
#pragma unroll
    for (int j = 0; j < 8; ++j) {
        float xs = x[j] * 128.0f;
        f16 hh = (f16)xs;
        h[j] = hh;
        l[j] = (f16)(xs - (float)hh);
    }
    f16* rp = dst + (size_t)row * 512 + dc * 64;
    *(f16x8*)(rp + q * 8)      = h;
    *(f16x8*)(rp + 32 + q * 8) = l;
}

__global__ __launch_bounds__(256) void vq_main_mfma(
    const float* __restrict__ z,         // [N, D] f32 (zsq + epilogue)
    const float* __restrict__ emb,       // [K, D] f32 (epilogue gather)
    const f16*  __restrict__ zhl,        // [N][512] split f16
    const f16*  __restrict__ ehl,        // [K][512] split f16
    const float* __restrict__ esq_g,     // [K]
    float* __restrict__ out_zq,
    float* __restrict__ out_codes,
    float* __restrict__ loss_acc)
{
    __shared__ f16 As[8192];             // 128 rows x 8 chunks x 8 f16 = 16 KB
    __shared__ f16 Bs[8192];             // 16 KB
    __shared__ float esq_s[KC];          // 4 KB
    __shared__ float zsq_s[BM];          // 512 B  -> 36.9 KB total

    const int tid  = threadIdx.x;
    const int row0 = blockIdx.x * BM;

    // ---- prologue: esq -> LDS, ||z||^2 for block rows (same assoc as R7) ----
    {
        float4 v = ((const float4*)esq_g)[tid];
        *(float4*)(esq_s + tid * 4) = v;
    }
    if (tid < BM) {
        const float4* zp = (const float4*)(z + (size_t)(row0 + tid) * DDIM);
        float s = 0.f;
        for (int q = 0; q < DQ; ++q) {
            float4 v = zp[q];
            s += v.x * v.x + v.y * v.y + v.z * v.z + v.w * v.w;
        }
        zsq_s[tid] = s;
    }

    // ---- staging descriptors: slot s = tid + 256*i; LDS linear, src swizzled
    const f16* a_src[4];
    const f16* b_src[4];
    f16* a_dst[4];
    f16* b_dst[4];
#pragma unroll
    for (int i = 0; i < 4; ++i) {
        int s = tid + 256 * i;
        int r = s >> 3;                      // tile row 0..127
        int c = (s & 7) ^ (r & 7);           // logical chunk for this slot
        a_src[i] = zhl + (size_t)(row0 + r) * 512 + c * 8;
        b_src[i] = ehl + (size_t)r * 512 + c * 8;     // + kt*65536 + dc*64
        a_dst[i] = As + s * 8;
        b_dst[i] = Bs + s * 8;
    }

    // ---- fragment read offsets (f16 units) ----
    const int wave  = tid >> 6;
    const int lane  = tid & 63;
    const int wr    = wave >> 1, wc = wave & 1;   // 2x2 waves over 128x128
    const int row16 = lane & 15;
    const int kg    = lane >> 4;                  // k-group 0..3
    const int m     = row16 & 7;
    const int coh   = (kg ^ m) * 8;               // h chunk, swizzled
    const int col_  = ((kg + 4) ^ m) * 8;         // l chunk, swizzled
    int aoff[4], boff[4];
#pragma unroll
    for (int i = 0; i < 4; ++i) {
        aoff[i] = (wr * 64 + i * 16 + row16) * 64;
        boff[i] = (wc * 64 + i * 16 + row16) * 64;
    }

    __syncthreads();
    float zsqr[16];
#pragma unroll
    for (int i = 0; i < 4; ++i)
#pragma unroll
        for (int t = 0; t < 4; ++t)
            zsqr[i * 4 + t] = zsq_s[wr * 64 + i * 16 + kg * 4 + t];

    float runv[16];
    int   runi[16];
#pragma unroll
    for (int i = 0; i < 16; ++i) { runv[i] = 3.4e38f; runi[i] = 0; }

#pragma unroll 1
    for (int kt = 0; kt < KC / BN; ++kt) {
        f32x4 acc[4][4];
        f32x4 zero = {0.f, 0.f, 0.f, 0.f};
#pragma unroll
        for (int i = 0; i < 4; ++i)
#pragma unroll
            for (int j = 0; j < 4; ++j) acc[i][j] = zero;

#pragma unroll 1
        for (int dc = 0; dc < DDIM / BD; ++dc) {
            __syncthreads();                      // prev reads done
            int off = dc * 64;
            size_t bo = (size_t)kt * 65536 + off;
#pragma unroll
            for (int i = 0; i < 4; ++i) {
                gl_lds16(a_src[i] + off, a_dst[i]);
                gl_lds16(b_src[i] + bo,  b_dst[i]);
            }
            __syncthreads();                      // vmcnt(0) drain

            f16x8 ah[4], al[4];
#pragma unroll
            for (int i = 0; i < 4; ++i) {
                ah[i] = *(const f16x8*)(As + aoff[i] + coh);
                al[i] = *(const f16x8*)(As + aoff[i] + col_);
            }
#pragma unroll
            for (int j = 0; j < 4; ++j) {
                f16x8 bh = *(const f16x8*)(Bs + boff[j] + coh);
                f16x8 bl = *(const f16x8*)(Bs + boff[j] + col_);
#pragma unroll
                for (int i = 0; i < 4; ++i) {
                    acc[i][j] = __builtin_amdgcn_mfma_f32_16x16x32_f16(ah[i], bh, acc[i][j], 0, 0, 0);
                    acc[i][j] = __builtin_amdgcn_mfma_f32_16x16x32_f16(ah[i], bl, acc[i][j], 0, 0, 0);
                    acc[i][j] = __builtin_amdgcn_mfma_f32_16x16x32_f16(al[i], bh, acc[i][j], 0, 0, 0);
                }
            }
        }

        // ---- fold k-tile into running argmin (cols ascending, strict <) ----
        // acc = 2^14 * g; -0x1p-13f * acc == -2g exactly (power-of-2 scale),
        // so fmaf(acc,-2^-13,zsq)+esq rounds exactly like ref (z_sq-2g)+e_sq.
#pragma unroll
        for (int j = 0; j < 4; ++j) {
            int col = kt * BN + wc * 64 + j * 16 + row16;
            float es = esq_s[col];
#pragma unroll
            for (int i = 0; i < 4; ++i) {
#pragma unroll
                for (int t = 0; t < 4; ++t) {
                    float d = fmaf(acc[i][j][t], -0x1p-13f, zsqr[i * 4 + t]) + es;
                    if (d < runv[i * 4 + t]) { runv[i * 4 + t] = d; runi[i * 4 + t] = col; }
                }
            }
        }
    }

    // ---- cross-thread argmin combine: 32 candidates per row ----
    __syncthreads();
    float* red_v = (float*)As;           // [128][32] f32 = 16 KB
    int*   red_i = (int*)Bs;             // [128][32] i32 = 16 KB
#pragma unroll
    for (int i = 0; i < 4; ++i)
#pragma unroll
        for (int t = 0; t < 4; ++t) {
            int lr = wr * 64 + i * 16 + kg * 4 + t;
            red_v[lr * 32 + wc * 16 + row16] = runv[i * 4 + t];
            red_i[lr * 32 + wc * 16 + row16] = runi[i * 4 + t];
        }
    __syncthreads();
    int* codes_s = (int*)zsq_s;
    if (tid < BM) {
        float bv = red_v[tid * 32];
        int   bi = red_i[tid * 32];
        for (int t = 1; t < 32; ++t) {
            float v  = red_v[tid * 32 + t];
            int   ix = red_i[tid * 32 + t];
            if (v < bv || (v == bv && ix < bi)) { bv = v; bi = ix; }
        }
        codes_s[tid] = bi;
        out_codes[row0 + tid] = (float)bi;
    }
    __syncthreads();

    // ---- epilogue: gather z_q (exact f32 emb), write z_q_st, loss partial ---
    float* lred = esq_s;                 // esq dead after last fold
    float lp = 0.f;
    for (int r = wave; r < BM; r += 4) {
        int code = codes_s[r];
        float4 e4 = *(const float4*)(emb + (size_t)code * DDIM + lane * 4);
        float4 z4 = *(const float4*)(z + (size_t)(row0 + r) * DDIM + lane * 4);
        float dx = e4.x - z4.x, dy = e4.y - z4.y, dz = e4.z - z4.z, dw = e4.w - z4.w;
        float4 o;
        o.x = z4.x + dx; o.y = z4.y + dy; o.z = z4.z + dz; o.w = z4.w + dw;
        *(float4*)(out_zq + (size_t)(row0 + r) * DDIM + lane * 4) = o;
        lp += dx * dx + dy * dy + dz * dz + dw * dw;
    }
    lred[tid] = lp;
    __syncthreads();
    for (int s = 128; s > 0; s >>= 1) {
        if (tid < s) lred[tid] += lred[tid + s];
        __syncthreads();
    }
    if (tid == 0) atomicAdd(loss_acc, lred[0]);
}

// ---------- R7 fp32 kernel, kept verbatim as ws_size fallback ----------
__global__ __launch_bounds__(256) void vq_main_f32(
    const float* __restrict__ z,
    const float* __restrict__ emb,
    const float* __restrict__ esq_g,
    float* __restrict__ out_zq,
    float* __restrict__ out_codes,
    float* __restrict__ loss_acc)
{
    __shared__ float zs[BM * LS];
    __shared__ float es[BN * LS];
    __shared__ float esq_s[KC];
    __shared__ float zsq_s[BM];
    float* red_v   = zs;
    int*   red_i   = (int*)(zs + 2048);
    int*   codes_s = (int*)es;
    float* lred    = es + 128;

    const int tid  = threadIdx.x;
    const int row0 = blockIdx.x * BM;
    const int trow = tid >> 4;
    const int tcol = tid & 15;

    {
        const float4* eg = (const float4*)esq_g;
        float4 v = eg[tid];
        *(float4*)(esq_s + tid * 4) = v;
    }
    if (tid < BM) {
        const float4* zp = (const float4*)(z + (size_t)(row0 + tid) * DDIM);
        float s = 0.f;
        for (int q = 0; q < DQ; ++q) {
            float4 v = zp[q];
            s += v.x * v.x + v.y * v.y + v.z * v.z + v.w * v.w;
        }
        zsq_s[tid] = s;
    }

    const int r0 = tid >> 3;
    const int q0 = tid & 7;
    const float* zp0 = z + (size_t)(row0 + r0) * DDIM + q0 * 4;
    const float* ep0 = emb + (size_t)r0 * DDIM + q0 * 4;
    const int ls0 = r0 * LS + q0 * 4;

    float4 pz[4], pe[4];
#pragma unroll
    for (int it = 0; it < 4; ++it) {
        pz[it] = *(const float4*)(zp0 + it * 32 * DDIM);
        pe[it] = *(const float4*)(ep0 + it * 32 * DDIM);
    }

    float runv[8];
    int   runi[8];
#pragma unroll
    for (int i = 0; i < 8; ++i) { runv[i] = 3.4e38f; runi[i] = 0; }

#pragma unroll 1
    for (int kt = 0; kt < KC / BN; ++kt) {
        float acc[8][8];
#pragma unroll
        for (int i = 0; i < 8; ++i)
#pragma unroll
            for (int j = 0; j < 8; ++j) acc[i][j] = 0.f;

#pragma unroll 1
        for (int dc = 0; dc < DDIM / BD; ++dc) {
            __syncthreads();
#pragma unroll
            for (int it = 0; it < 4; ++it) {
                int o = ls0 + it * 32 * LS;
                *(float2*)(zs + o)     = make_float2(pz[it].x, pz[it].y);
                *(float2*)(zs + o + 2) = make_float2(pz[it].z, pz[it].w);
                *(float2*)(es + o)     = make_float2(pe[it].x, pe[it].y);
                *(float2*)(es + o + 2) = make_float2(pe[it].z, pe[it].w);
            }
            __syncthreads();
            {
                int ndc = dc + 1, nkt = kt;
                if (ndc == DDIM / BD) { ndc = 0; ++nkt; }
                if (nkt < KC / BN) {
                    size_t zo = (size_t)ndc * BD;
                    size_t eo = (size_t)nkt * BN * DDIM + (size_t)ndc * BD;
#pragma unroll
                    for (int it = 0; it < 4; ++it) {
                        pz[it] = *(const float4*)(zp0 + it * 32 * DDIM + zo);
                        pe[it] = *(const float4*)(ep0 + it * 32 * DDIM + eo);
                    }
                }
            }
#pragma unroll
            for (int s = 0; s < BD / 2; ++s) {
                float2 a2[8], b2[8];
#pragma unroll
                for (int i = 0; i < 8; ++i)
                    a2[i] = *(const float2*)(zs + (trow + 16 * i) * LS + s * 2);
#pragma unroll
                for (int j = 0; j < 8; ++j)
                    b2[j] = *(const float2*)(es + (tcol + 16 * j) * LS + s * 2);
#pragma unroll
                for (int i = 0; i < 8; ++i)
#pragma unroll
                    for (int j = 0; j < 8; ++j)
                        acc[i][j] = fmaf(a2[i].y, b2[j].y,
                                     fmaf(a2[i].x, b2[j].x, acc[i][j]));
            }
        }
#pragma unroll
        for (int i = 0; i < 8; ++i) {
            float zq2 = zsq_s[trow + 16 * i];
#pragma unroll
            for (int j = 0; j < 8; ++j) {
                int col = kt * BN + tcol + 16 * j;
                float dist = zq2 - 2.f * acc[i][j] + esq_s[col];
                if (dist < runv[i]) { runv[i] = dist; runi[i] = col; }
            }
        }
    }

    __syncthreads();
#pragma unroll
    for (int i = 0; i < 8; ++i) {
        int lr = trow + 16 * i;
        red_v[lr * 16 + tcol] = runv[i];
        red_i[lr * 16 + tcol] = runi[i];
    }
    __syncthreads();
    if (tid < BM) {
        float bv = red_v[tid * 16];
        int   bi = red_i[tid * 16];
        for (int t = 1; t < 16; ++t) {
            float v  = red_v[tid * 16 + t];
            int   ix = red_i[tid * 16 + t];
            if (v < bv || (v == bv && ix < bi)) { bv = v; bi = ix; }
        }
        codes_s[tid] = bi;
        out_codes[row0 + tid] = (float)bi;
    }
    __syncthreads();

    const int wavf = tid >> 6;
    const int lanf = tid & 63;
    float lp = 0.f;
    for (int r = wavf; r < BM; r += 4) {
        int code = codes_s[r];
        float4 e4 = *(const float4*)(emb + (size_t)code * DDIM + lanf * 4);
        float4 z4 = *(const float4*)(z + (size_t)(row0 + r) * DDIM + lanf * 4);
        float dx = e4.x - z4.x, dy = e4.y - z4.y, dz = e4.z - z4.z, dw = e4.w - z4.w;
        float4 o;
        o.x = z4.x + dx; o.y = z4.y + dy; o.z = z4.z + dz; o.w = z4.w + dw;
        *(float4*)(out_zq + (size_t)(row0 + r) * DDIM + lanf * 4) = o;
        lp += dx * dx + dy * dy + dz * dz + dw * dw;
    }
    lred[tid] = lp;
    __syncthreads();
    for (int s = 128; s > 0; s >>= 1) {
        if (tid < s) lred[tid] += lred[tid + s];
        __syncthreads();
    }
    if (tid == 0) atomicAdd(loss_acc, lred[0]);
}

// One block per code k; scan codes (L2-resident), gather rows coalesced.
__global__ __launch_bounds__(256) void vq_scatter(
    const float* __restrict__ z,
    const float* __restrict__ codes_f,
    float* __restrict__ embed_sum,
    float* __restrict__ counts)
{
    __shared__ int list[1024];
    __shared__ int nmatch;
    const int k   = blockIdx.x;
    const int tid = threadIdx.x;

    float acc = 0.f;
    int total = 0;
    if (tid == 0) nmatch = 0;
    __syncthreads();

    for (int base = 0; base < NROW; base += 1024) {
        float4 c4 = *(const float4*)(codes_f + base + tid * 4);
        int i0 = base + tid * 4;
        if ((int)c4.x == k) { int p = atomicAdd(&nmatch, 1); list[p] = i0; }
        if ((int)c4.y == k) { int p = atomicAdd(&nmatch, 1); list[p] = i0 + 1; }
        if ((int)c4.z == k) { int p = atomicAdd(&nmatch, 1); list[p] = i0 + 2; }
        if ((int)c4.w == k) { int p = atomicAdd(&nmatch, 1); list[p] = i0 + 3; }
        __syncthreads();
        int nm = nmatch;
        for (int i = 0; i < nm; ++i)
            acc += z[(size_t)list[i] * DDIM + tid];
        total += nm;
        __syncthreads();
        if (tid == 0) nmatch = 0;
        __syncthreads();
    }
    embed_sum[(size_t)k * DDIM + tid] = acc;
    if (tid == 0) counts[k] = (float)total;
}

__global__ void vq_finalize(const float* __restrict__ cluster_size,
                            const float* __restrict__ counts,
                            const float* __restrict__ loss_acc,
                            float* __restrict__ out_ncs,
                            float* __restrict__ out_loss,
                            float* __restrict__ cs_sm,
                            float inv_ND)
{
    __shared__ float sred[KC];
    const int tid = threadIdx.x;
    float ncs = cluster_size[tid] * DECAYF + counts[tid] * OMDF;
    out_ncs[tid] = ncs;
    sred[tid] = ncs;
    __syncthreads();
    for (int s = KC / 2; s > 0; s >>= 1) {
        if (tid < s) sred[tid] += sred[tid + s];
        __syncthreads();
    }
    float n = sred[0];
    cs_sm[tid] = (ncs + EPSF) / (n + (float)KC * EPSF) * n;
    if (tid == 0) out_loss[0] = BETAF * loss_acc[0] * inv_ND;
}

__global__ void vq_embed(const float* __restrict__ embed_avg,
                         const float* __restrict__ embed_sum,
                         const float* __restrict__ cs_sm,
                         float* __restrict__ out_nea,
                         float* __restrict__ out_nemb)
{
    int idx = blockIdx.x * blockDim.x + threadIdx.x;
    int k = idx >> 6;
    float4 ea = ((const float4*)embed_avg)[idx];
    float4 s4 = ((const float4*)embed_sum)[idx];
    float4 nea;
    nea.x = ea.x * DECAYF + s4.x * OMDF;
    nea.y = ea.y * DECAYF + s4.y * OMDF;
    nea.z = ea.z * DECAYF + s4.z * OMDF;
    nea.w = ea.w * DECAYF + s4.w * OMDF;
    ((float4*)out_nea)[idx] = nea;
    float cs = cs_sm[k];
    float4 ne;
    ne.x = nea.x / cs; ne.y = nea.y / cs; ne.z = nea.z / cs; ne.w = nea.w / cs;
    ((float4*)out_nemb)[idx] = ne;
}

extern "C" void kernel_launch(void* const* d_in, const int* in_sizes, int n_in,
                              void* d_out, int out_size, void* d_ws, size_t ws_size,
                              hipStream_t stream) {
    const float* z            = (const float*)d_in[0];   // [N, 256]
    const float* emb          = (const float*)d_in[1];   // [1024, 256]
    const float* cluster_size = (const float*)d_in[2];   // [1024]
    const float* embed_avg    = (const float*)d_in[3];   // [1024, 256]

    const int ND = in_sizes[0];       // N*D = 16777216
    const int KD = in_sizes[1];       // K*D = 262144
    const int K  = in_sizes[2];       // 1024
    const int N  = ND / DDIM;         // 65536

    float* out       = (float*)d_out;
    float* out_zq    = out;
    float* out_loss  = out + (size_t)ND;
    float* out_codes = out + (size_t)ND + 1;
    float* out_nemb  = out + (size_t)ND + 1 + N;
    float* out_ncs   = out_nemb + (size_t)KD;
    float* out_nea   = out_ncs + (size_t)K;

    float* ws        = (float*)d_ws;
    float* loss_acc  = ws;                 // [1]
    float* counts    = ws + 1;             // [K]
    float* cs_sm     = counts + K;         // [K]
    float* esq_g     = cs_sm + K;          // [K]
    float* embed_sum = esq_g + K;          // [K*D]

    size_t base_floats = (size_t)1 + 3 * (size_t)K + (size_t)KD;
    size_t f16_off = (base_floats * sizeof(float) + 255) & ~(size_t)255;
    size_t zbytes  = (size_t)N * 512 * sizeof(f16);      // 64 MB
    size_t ebytes  = (size_t)K * 512 * sizeof(f16);      // 1 MB
    bool mfma_ok   = ws_size >= f16_off + zbytes + ebytes;

    hipMemsetAsync(loss_acc, 0, sizeof(float), stream);
    vq_esq<<<K / 256, 256, 0, stream>>>(emb, esq_g);
    if (mfma_ok) {
        f16* zhl = (f16*)((char*)d_ws + f16_off);
        f16* ehl = (f16*)((char*)d_ws + f16_off + zbytes);
        vq_prep<<<(N * 32) / 256, 256, 0, stream>>>(z, zhl);
        vq_prep<<<(K * 32) / 256, 256, 0, stream>>>(emb, ehl);
        vq_main_mfma<<<N / BM, 256, 0, stream>>>(z, emb, zhl, ehl, esq_g,
                                                 out_zq, out_codes, loss_acc);
    } else {
        vq_main_f32<<<N / BM, 256, 0, stream>>>(z, emb, esq_g,
                                                out_zq, out_codes, loss_acc);
    }
    vq_scatter<<<K, 256, 0, stream>>>(z, out_codes, embed_sum, counts);
    vq_finalize<<<1, K, 0, stream>>>(cluster_size, counts, loss_acc,
                                     out_ncs, out_loss, cs_sm, 1.0f / (float)ND);
    vq_embed<<<KD / 1024, 256, 0, stream>>>(embed_avg, embed_sum, cs_sm,
                                            out_nea, out_nemb);
}

// Round 2
// 321.105 us; speedup vs baseline: 2.8277x; 1.0511x over previous
//
#include <hip/hip_runtime.h>

// VQ-VAE EMA vector quantizer, fp32 in/out.
// N=65536 rows (32*2048), D=256, K=1024 codes.
//
// R8: distance GEMM on matrix cores via double-f16 split (3x mfma per K32):
//     128*z = zh+zl, 128*e = eh+el; acc = zh*eh + zh*el + zl*eh (fp32 acc).
//     Exact power-of-2 descale in the fold: d = fmaf(acc,-0x1p-13f,zsq)+esq.
//     908 -> 337 us, main kernel 143 us @ MfmaUtil 31%.
// R9: the 2-barrier-per-K-step structure ceilings at ~36% MfmaUtil (m97
//     class: __syncthreads forces vmcnt(0) drain every 32-K step). Rebuilt
//     as flat K'=768 GEMM (planes: steps 0-3 zh*eh, 4-7 zh*el, 8-11 zl*eh),
//     256x128 tile, 512 thr (8 waves 4Mx2N), BK=64, TRI-buffered LDS
//     (144 KB dynamic) with counted s_waitcnt vmcnt(6): stage g+2 issued at
//     step g, so 6 loads stay in flight across every raw s_barrier.
//     zsq/esq fused into prep (shfl tree); main no longer re-reads z in
//     prologue. setprio(1) around MFMA cluster. Argmin combine transposed
//     (+pad 258) -- old scan was a 64-way bank conflict.

#define DDIM 256
#define DQ   64
#define KC   1024
#define NROW 65536
#define BM   128     // fp32-fallback tile
#define BN   128
#define BD   32
#define LS   34
#define DECAYF 0.99f
#define OMDF   0.01f
#define BETAF  0.25f
#define EPSF   1e-5f

// R9 mfma geometry
#define BMR  256     // rows per block
#define BNC  128     // cols per n-tile
#define NT8  8       // n-tiles (1024/128)
#define KST  12      // K-steps per n-tile (768/64)
#define ABUF 16384   // f16 per A buffer (256*64)
#define BBUF 8192    // f16 per B buffer (128*64)
#define SMEM_BYTES (3*ABUF*2 + 3*BBUF*2 + 4096)   // 151552 B

typedef _Float16 f16;
typedef _Float16 f16x8 __attribute__((ext_vector_type(8)));
typedef float    f32x4 __attribute__((ext_vector_type(4)));

__device__ __forceinline__ void gl_lds16(const f16* g, f16* l) {
    __builtin_amdgcn_global_load_lds(
        (const __attribute__((address_space(1))) void*)g,
        (__attribute__((address_space(3))) void*)l, 16, 0, 0);
}

// one-shot ||e||^2 (fallback path only; mfma path gets esq from vq_prep)
__global__ __launch_bounds__(256) void vq_esq(const float* __restrict__ emb,
                                              float* __restrict__ esq_g)
{
    int k = blockIdx.x * 256 + threadIdx.x;
    const float4* ep = (const float4*)(emb + (size_t)k * DDIM);
    float s = 0.f;
    for (int q = 0; q < DQ; ++q) {
        float4 v = ep[q];
        s += v.x * v.x + v.y * v.y + v.z * v.z + v.w * v.w;
    }
    esq_g[k] = s;
}

// f32 -> double-f16 split, plane layout [row][zh(256) | zl(256)] f16.
// Also emits ||x||^2 per row (8-elem partials + 32-lane shfl tree).
__global__ __launch_bounds__(256) void vq_prep(const float* __restrict__ src,
                                               f16* __restrict__ dst,
                                               float* __restrict__ sq_g)
{
    int t   = blockIdx.x * 256 + threadIdx.x;   // 8-elem chunk id
    int row = t >> 5;                           // 32 chunks per row
    int c   = t & 31;
    const float4* sp = (const float4*)(src + (size_t)row * DDIM + c * 8);
    float4 v0 = sp[0], v1 = sp[1];
    float x[8] = {v0.x, v0.y, v0.z, v0.w, v1.x, v1.y, v1.z, v1.w};
    f16x8 h, l;
    float s = 0.f;
#pragma unroll
    for (int j = 0; j < 8; ++j) {
        float xs = x[j] * 128.0f;
        f16 hh = (f16)xs;
        h[j] = hh;
        l[j] = (f16)(xs - (float)hh);
        s += x[j] * x[j];
    }
    f16* rp = dst + (size_t)row * 512;
    *(f16x8*)(rp + c * 8)       = h;
    *(f16x8*)(rp + 256 + c * 8) = l;
    s += __shfl_xor(s, 1);
    s += __shfl_xor(s, 2);
    s += __shfl_xor(s, 4);
    s += __shfl_xor(s, 8);
    s += __shfl_xor(s, 16);
    if (c == 0) sq_g[row] = s;
}

// Stage: per thread 4 A-loads + 2 B-loads of 16 B. LDS linear dest,
// inverse-XOR-swizzled global source (involution; rule both-sides).
#define STAGE9(s_, nt_, b_) do {                                           \
    int grp_ = (s_) >> 2, sm_ = (s_) & 3;                                  \
    int ao_ = ((grp_ == 2) ? 256 : 0) + sm_ * 64;                          \
    int bo_ = ((grp_ == 1) ? 256 : 0) + sm_ * 64;                          \
    f16* ad_ = Al + (b_) * ABUF + tid * 8;                                 \
    const f16* as_ = asrc0 + ao_;                                          \
    gl_lds16(as_,             ad_);                                        \
    gl_lds16(as_ +  64 * 512, ad_ + 4096);                                 \
    gl_lds16(as_ + 128 * 512, ad_ + 8192);                                 \
    gl_lds16(as_ + 192 * 512, ad_ + 12288);                                \
    f16* bd_ = Bl + (b_) * BBUF + tid * 8;                                 \
    const f16* bs_ = bsrc0 + (size_t)(nt_) * 65536 + bo_;                  \
    gl_lds16(bs_,            bd_);                                         \
    gl_lds16(bs_ + 64 * 512, bd_ + 4096);                                  \
} while (0)

__global__ __launch_bounds__(512) void vq_main_mfma(
    const float* __restrict__ z,         // [N, D] f32 (epilogue)
    const float* __restrict__ emb,       // [K, D] f32 (epilogue gather)
    const f16*  __restrict__ zhl,        // [N][zh 256 | zl 256] f16
    const f16*  __restrict__ ehl,        // [K][eh 256 | el 256] f16
    const float* __restrict__ esq_g,     // [K]
    const float* __restrict__ zsq_g,     // [N]
    float* __restrict__ out_zq,
    float* __restrict__ out_codes,
    float* __restrict__ loss_acc)
{
    extern __shared__ f16 smem[];
    f16* Al = smem;                              // 3 x 32 KB
    f16* Bl = smem + 3 * ABUF;                   // 3 x 16 KB
    float* esq_s = (float*)(smem + 3 * ABUF + 3 * BBUF);  // 4 KB

    const int tid  = threadIdx.x;
    const int row0 = blockIdx.x * BMR;
    const int wave = tid >> 6, lane = tid & 63;
    const int wr = wave >> 1, wc = wave & 1;     // 4 M-groups x 2 N-groups
    const int row16 = lane & 15, kg = lane >> 4;

    // esq -> LDS (visible to all waves after prologue barrier)
    { float2 v = ((const float2*)esq_g)[tid];
      *(float2*)(esq_s + tid * 2) = v; }

    // zsq -> registers; pin so the compiler resolves the vmcnt here,
    // not with a drain in the middle of the pipelined loop.
    float zsqr[16];
#pragma unroll
    for (int i = 0; i < 4; ++i)
#pragma unroll
        for (int t = 0; t < 4; ++t)
            zsqr[i * 4 + t] = zsq_g[row0 + wr * 64 + i * 16 + kg * 4 + t];
#pragma unroll
    for (int q = 0; q < 16; ++q) asm volatile("" :: "v"(zsqr[q]));

    // stage source descriptors (slot = tid + 512*it; row = slot>>3, c' = slot&7)
    const int arow = tid >> 3;                       // 0..63
    const int axor = ((tid & 7) ^ (arow & 7)) * 8;   // chunk XOR, f16 units
    const f16* asrc0 = zhl + (size_t)(row0 + arow) * 512 + axor;
    const f16* bsrc0 = ehl + (size_t)arow * 512 + axor;

    // fragment LDS offsets (f16 units), swizzled to match staging
    int aofs[4][2], bofs[4][2];
#pragma unroll
    for (int i = 0; i < 4; ++i)
#pragma unroll
        for (int kk = 0; kk < 2; ++kk) {
            int ra = wr * 64 + i * 16 + row16;
            aofs[i][kk] = ra * 64 + (((kk * 4 + kg) ^ (ra & 7)) * 8);
            int rb = wc * 64 + i * 16 + row16;
            bofs[i][kk] = rb * 64 + (((kk * 4 + kg) ^ (rb & 7)) * 8);
        }

    // ---- prologue: stage steps 0,1; wait oldest 6 (= stage 0); barrier ----
    STAGE9(0, 0, 0);
    STAGE9(1, 0, 1);
    asm volatile("s_waitcnt lgkmcnt(0)" ::: "memory");  // esq ds_write done
    asm volatile("s_waitcnt vmcnt(6)" ::: "memory");
    __builtin_amdgcn_s_barrier();

    float runv[16]; int runi[16];
#pragma unroll
    for (int q = 0; q < 16; ++q) { runv[q] = 3.4e38f; runi[q] = 0; }

    int s2 = 2, nt2 = 0, b2 = 2, bc = 0;   // next-next stage coords / buffers

#pragma unroll 1
    for (int nt = 0; nt < NT8; ++nt) {
        f32x4 acc[4][4];
        f32x4 zero4 = {0.f, 0.f, 0.f, 0.f};
#pragma unroll
        for (int i = 0; i < 4; ++i)
#pragma unroll
            for (int j = 0; j < 4; ++j) acc[i][j] = zero4;

#pragma unroll 1
        for (int s = 0; s < KST; ++s) {
            // issue stage g+2 into the buffer freed at the last barrier
            STAGE9(s2, nt2, b2);
            ++s2; if (s2 == KST) { s2 = 0; ++nt2; if (nt2 == NT8) nt2 = 0; }
            ++b2; if (b2 == 3) b2 = 0;

            const f16* Ab = Al + bc * ABUF;
            const f16* Bb = Bl + bc * BBUF;
            __builtin_amdgcn_s_setprio(1);
#pragma unroll
            for (int kk = 0; kk < 2; ++kk) {
                f16x8 af0 = *(const f16x8*)(Ab + aofs[0][kk]);
                f16x8 af1 = *(const f16x8*)(Ab + aofs[1][kk]);
                f16x8 af2 = *(const f16x8*)(Ab + aofs[2][kk]);
                f16x8 af3 = *(const f16x8*)(Ab + aofs[3][kk]);
                f16x8 bf0 = *(const f16x8*)(Bb + bofs[0][kk]);
                f16x8 bf1 = *(const f16x8*)(Bb + bofs[1][kk]);
                f16x8 bf2 = *(const f16x8*)(Bb + bofs[2][kk]);
                f16x8 bf3 = *(const f16x8*)(Bb + bofs[3][kk]);
                acc[0][0] = __builtin_amdgcn_mfma_f32_16x16x32_f16(af0, bf0, acc[0][0], 0, 0, 0);
                acc[1][0] = __builtin_amdgcn_mfma_f32_16x16x32_f16(af1, bf0, acc[1][0], 0, 0, 0);
                acc[2][0] = __builtin_amdgcn_mfma_f32_16x16x32_f16(af2, bf0, acc[2][0], 0, 0, 0);
                acc[3][0] = __builtin_amdgcn_mfma_f32_16x16x32_f16(af3, bf0, acc[3][0], 0, 0, 0);
                acc[0][1] = __builtin_amdgcn_mfma_f32_16x16x32_f16(af0, bf1, acc[0][1], 0, 0, 0);
                acc[1][1] = __builtin_amdgcn_mfma_f32_16x16x32_f16(af1, bf1, acc[1][1], 0, 0, 0);
                acc[2][1] = __builtin_amdgcn_mfma_f32_16x16x32_f16(af2, bf1, acc[2][1], 0, 0, 0);
                acc[3][1] = __builtin_amdgcn_mfma_f32_16x16x32_f16(af3, bf1, acc[3][1], 0, 0, 0);
                acc[0][2] = __builtin_amdgcn_mfma_f32_16x16x32_f16(af0, bf2, acc[0][2], 0, 0, 0);
                acc[1][2] = __builtin_amdgcn_mfma_f32_16x16x32_f16(af1, bf2, acc[1][2], 0, 0, 0);
                acc[2][2] = __builtin_amdgcn_mfma_f32_16x16x32_f16(af2, bf2, acc[2][2], 0, 0, 0);
                acc[3][2] = __builtin_amdgcn_mfma_f32_16x16x32_f16(af3, bf2, acc[3][2], 0, 0, 0);
                acc[0][3] = __builtin_amdgcn_mfma_f32_16x16x32_f16(af0, bf3, acc[0][3], 0, 0, 0);
                acc[1][3] = __builtin_amdgcn_mfma_f32_16x16x32_f16(af1, bf3, acc[1][3], 0, 0, 0);
                acc[2][3] = __builtin_amdgcn_mfma_f32_16x16x32_f16(af2, bf3, acc[2][3], 0, 0, 0);
                acc[3][3] = __builtin_amdgcn_mfma_f32_16x16x32_f16(af3, bf3, acc[3][3], 0, 0, 0);
            }
            __builtin_amdgcn_s_setprio(0);
            ++bc; if (bc == 3) bc = 0;
            // counted: retire stage g+1 (next step's buffer); leave g+2 in flight
            asm volatile("s_waitcnt vmcnt(6)" ::: "memory");
            __builtin_amdgcn_s_barrier();
        }

        // ---- fold n-tile into running argmin (nt asc, cols asc, strict <) --
        // acc = 2^14*g; fmaf(acc,-0x1p-13f,zsq)+esq rounds like (zsq-2g)+esq.
#pragma unroll
        for (int j = 0; j < 4; ++j) {
            int col = nt * BNC + wc * 64 + j * 16 + row16;
            float es = esq_s[col];
#pragma unroll
            for (int i = 0; i < 4; ++i)
#pragma unroll
                for (int t = 0; t < 4; ++t) {
                    float d = fmaf(acc[i][j][t], -0x1p-13f, zsqr[i * 4 + t]) + es;
                    if (d < runv[i * 4 + t]) { runv[i * 4 + t] = d; runi[i * 4 + t] = col; }
                }
        }
    }

    // ---- cross-thread argmin combine: 32 candidates/row, transposed+padded
    __syncthreads();                         // drains wrap stages too
    float* red_v = (float*)Al;               // [32][258] c-major
    int*   red_i = (int*)((float*)Al + 32 * 258);
#pragma unroll
    for (int i = 0; i < 4; ++i)
#pragma unroll
        for (int t = 0; t < 4; ++t) {
            int r = wr * 64 + i * 16 + kg * 4 + t;
            int c = wc * 16 + row16;
            red_v[c * 258 + r] = runv[i * 4 + t];
            red_i[c * 258 + r] = runi[i * 4 + t];
        }
    __syncthreads();
    int* codes_s = (int*)Bl;
    if (tid < BMR) {
        float bv = red_v[tid];
        int   bi = red_i[tid];
#pragma unroll 1
        for (int t = 1; t < 32; ++t) {
            float v  = red_v[t * 258 + tid];
            int   ix = red_i[t * 258 + tid];
            if (v < bv || (v == bv && ix < bi)) { bv = v; bi = ix; }
        }
        codes_s[tid] = bi;
        out_codes[row0 + tid] = (float)bi;
    }
    __syncthreads();

    // ---- epilogue: gather z_q (exact f32), write z_q_st, loss partial ----
    float* lred = (float*)Bl + 256;
    float lp = 0.f;
#pragma unroll 1
    for (int r = wave; r < BMR; r += 8) {
        int code = codes_s[r];
        float4 e4 = *(const float4*)(emb + (size_t)code * DDIM + lane * 4);
        float4 z4 = *(const float4*)(z + (size_t)(row0 + r) * DDIM + lane * 4);
        float dx = e4.x - z4.x, dy = e4.y - z4.y, dz = e4.z - z4.z, dw = e4.w - z4.w;
        float4 o;
        o.x = z4.x + dx; o.y = z4.y + dy; o.z = z4.z + dz; o.w = z4.w + dw;
        *(float4*)(out_zq + (size_t)(row0 + r) * DDIM + lane * 4) = o;
        lp += dx * dx + dy * dy + dz * dz + dw * dw;
    }
    lred[tid] = lp;
    __syncthreads();
    for (int st = 256; st > 0; st >>= 1) {
        if (tid < st) lred[tid] += lred[tid + st];
        __syncthreads();
    }
    if (tid == 0) atomicAdd(loss_acc, lred[0]);
}

// ---------- R7 fp32 kernel, kept verbatim as ws_size fallback ----------
__global__ __launch_bounds__(256) void vq_main_f32(
    const float* __restrict__ z,
    const float* __restrict__ emb,
    const float* __restrict__ esq_g,
    float* __restrict__ out_zq,
    float* __restrict__ out_codes,
    float* __restrict__ loss_acc)
{
    __shared__ float zs[BM * LS];
    __shared__ float es[BN * LS];
    __shared__ float esq_s[KC];
    __shared__ float zsq_s[BM];
    float* red_v   = zs;
    int*   red_i   = (int*)(zs + 2048);
    int*   codes_s = (int*)es;
    float* lred    = es + 128;

    const int tid  = threadIdx.x;
    const int row0 = blockIdx.x * BM;
    const int trow = tid >> 4;
    const int tcol = tid & 15;

    {
        const float4* eg = (const float4*)esq_g;
        float4 v = eg[tid];
        *(float4*)(esq_s + tid * 4) = v;
    }
    if (tid < BM) {
        const float4* zp = (const float4*)(z + (size_t)(row0 + tid) * DDIM);
        float s = 0.f;
        for (int q = 0; q < DQ; ++q) {
            float4 v = zp[q];
            s += v.x * v.x + v.y * v.y + v.z * v.z + v.w * v.w;
        }
        zsq_s[tid] = s;
    }

    const int r0 = tid >> 3;
    const int q0 = tid & 7;
    const float* zp0 = z + (size_t)(row0 + r0) * DDIM + q0 * 4;
    const float* ep0 = emb + (size_t)r0 * DDIM + q0 * 4;
    const int ls0 = r0 * LS + q0 * 4;

    float4 pz[4], pe[4];
#pragma unroll
    for (int it = 0; it < 4; ++it) {
        pz[it] = *(const float4*)(zp0 + it * 32 * DDIM);
        pe[it] = *(const float4*)(ep0 + it * 32 * DDIM);
    }

    float runv[8];
    int   runi[8];
#pragma unroll
    for (int i = 0; i < 8; ++i) { runv[i] = 3.4e38f; runi[i] = 0; }

#pragma unroll 1
    for (int kt = 0; kt < KC / BN; ++kt) {
        float acc[8][8];
#pragma unroll
        for (int i = 0; i < 8; ++i)
#pragma unroll
            for (int j = 0; j < 8; ++j) acc[i][j] = 0.f;

#pragma unroll 1
        for (int dc = 0; dc < DDIM / BD; ++dc) {
            __syncthreads();
#pragma unroll
            for (int it = 0; it < 4; ++it) {
                int o = ls0 + it * 32 * LS;
                *(float2*)(zs + o)     = make_float2(pz[it].x, pz[it].y);
                *(float2*)(zs + o + 2) = make_float2(pz[it].z, pz[it].w);
                *(float2*)(es + o)     = make_float2(pe[it].x, pe[it].y);
                *(float2*)(es + o + 2) = make_float2(pe[it].z, pe[it].w);
            }
            __syncthreads();
            {
                int ndc = dc + 1, nkt = kt;
                if (ndc == DDIM / BD) { ndc = 0; ++nkt; }
                if (nkt < KC / BN) {
                    size_t zo = (size_t)ndc * BD;
                    size_t eo = (size_t)nkt * BN * DDIM + (size_t)ndc * BD;
#pragma unroll
                    for (int it = 0; it < 4; ++it) {
                        pz[it] = *(const float4*)(zp0 + it * 32 * DDIM + zo);
                        pe[it] = *(const float4*)(ep0 + it * 32 * DDIM + eo);
                    }
                }
            }
#pragma unroll
            for (int s = 0; s < BD / 2; ++s) {
                float2 a2[8], b2[8];
#pragma unroll
                for (int i = 0; i < 8; ++i)
                    a2[i] = *(const float2*)(zs + (trow + 16 * i) * LS + s * 2);
#pragma unroll
                for (int j = 0; j < 8; ++j)
                    b2[j] = *(const float2*)(es + (tcol + 16 * j) * LS + s * 2);
#pragma unroll
                for (int i = 0; i < 8; ++i)
#pragma unroll
                    for (int j = 0; j < 8; ++j)
                        acc[i][j] = fmaf(a2[i].y, b2[j].y,
                                     fmaf(a2[i].x, b2[j].x, acc[i][j]));
            }
        }
#pragma unroll
        for (int i = 0; i < 8; ++i) {
            float zq2 = zsq_s[trow + 16 * i];
#pragma unroll
            for (int j = 0; j < 8; ++j) {
                int col = kt * BN + tcol + 16 * j;
                float dist = zq2 - 2.f * acc[i][j] + esq_s[col];
                if (dist < runv[i]) { runv[i] = dist; runi[i] = col; }
            }
        }
    }

    __syncthreads();
#pragma unroll
    for (int i = 0; i < 8; ++i) {
        int lr = trow + 16 * i;
        red_v[lr * 16 + tcol] = runv[i];
        red_i[lr * 16 + tcol] = runi[i];
    }
    __syncthreads();
    if (tid < BM) {
        float bv = red_v[tid * 16];
        int   bi = red_i[tid * 16];
        for (int t = 1; t < 16; ++t) {
            float v  = red_v[tid * 16 + t];
            int   ix = red_i[tid * 16 + t];
            if (v < bv || (v == bv && ix < bi)) { bv = v; bi = ix; }
        }
        codes_s[tid] = bi;
        out_codes[row0 + tid] = (float)bi;
    }
    __syncthreads();

    const int wavf = tid >> 6;
    const int lanf = tid & 63;
    float lp = 0.f;
    for (int r = wavf; r < BM; r += 4) {
        int code = codes_s[r];
        float4 e4 = *(const float4*)(emb + (size_t)code * DDIM + lanf * 4);
        float4 z4 = *(const float4*)(z + (size_t)(row0 + r) * DDIM + lanf * 4);
        float dx = e4.x - z4.x, dy = e4.y - z4.y, dz = e4.z - z4.z, dw = e4.w - z4.w;
        float4 o;
        o.x = z4.x + dx; o.y = z4.y + dy; o.z = z4.z + dz; o.w = z4.w + dw;
        *(float4*)(out_zq + (size_t)(row0 + r) * DDIM + lanf * 4) = o;
        lp += dx * dx + dy * dy + dz * dz + dw * dw;
    }
    lred[tid] = lp;
    __syncthreads();
    for (int s = 128; s > 0; s >>= 1) {
        if (tid < s) lred[tid] += lred[tid + s];
        __syncthreads();
    }
    if (tid == 0) atomicAdd(loss_acc, lred[0]);
}

// One block per code k; scan codes (L2-resident), gather rows coalesced.
__global__ __launch_bounds__(256) void vq_scatter(
    const float* __restrict__ z,
    const float* __restrict__ codes_f,
    float* __restrict__ embed_sum,
    float* __restrict__ counts)
{
    __shared__ int list[1024];
    __shared__ int nmatch;
    const int k   = blockIdx.x;
    const int tid = threadIdx.x;

    float acc = 0.f;
    int total = 0;
    if (tid == 0) nmatch = 0;
    __syncthreads();

    for (int base = 0; base < NROW; base += 1024) {
        float4 c4 = *(const float4*)(codes_f + base + tid * 4);
        int i0 = base + tid * 4;
        if ((int)c4.x == k) { int p = atomicAdd(&nmatch, 1); list[p] = i0; }
        if ((int)c4.y == k) { int p = atomicAdd(&nmatch, 1); list[p] = i0 + 1; }
        if ((int)c4.z == k) { int p = atomicAdd(&nmatch, 1); list[p] = i0 + 2; }
        if ((int)c4.w == k) { int p = atomicAdd(&nmatch, 1); list[p] = i0 + 3; }
        __syncthreads();
        int nm = nmatch;
        for (int i = 0; i < nm; ++i)
            acc += z[(size_t)list[i] * DDIM + tid];
        total += nm;
        __syncthreads();
        if (tid == 0) nmatch = 0;
        __syncthreads();
    }
    embed_sum[(size_t)k * DDIM + tid] = acc;
    if (tid == 0) counts[k] = (float)total;
}

__global__ void vq_finalize(const float* __restrict__ cluster_size,
                            const float* __restrict__ counts,
                            const float* __restrict__ loss_acc,
                            float* __restrict__ out_ncs,
                            float* __restrict__ out_loss,
                            float* __restrict__ cs_sm,
                            float inv_ND)
{
    __shared__ float sred[KC];
    const int tid = threadIdx.x;
    float ncs = cluster_size[tid] * DECAYF + counts[tid] * OMDF;
    out_ncs[tid] = ncs;
    sred[tid] = ncs;
    __syncthreads();
    for (int s = KC / 2; s > 0; s >>= 1) {
        if (tid < s) sred[tid] += sred[tid + s];
        __syncthreads();
    }
    float n = sred[0];
    cs_sm[tid] = (ncs + EPSF) / (n + (float)KC * EPSF) * n;
    if (tid == 0) out_loss[0] = BETAF * loss_acc[0] * inv_ND;
}

__global__ void vq_embed(const float* __restrict__ embed_avg,
                         const float* __restrict__ embed_sum,
                         const float* __restrict__ cs_sm,
                         float* __restrict__ out_nea,
                         float* __restrict__ out_nemb)
{
    int idx = blockIdx.x * blockDim.x + threadIdx.x;
    int k = idx >> 6;
    float4 ea = ((const float4*)embed_avg)[idx];
    float4 s4 = ((const float4*)embed_sum)[idx];
    float4 nea;
    nea.x = ea.x * DECAYF + s4.x * OMDF;
    nea.y = ea.y * DECAYF + s4.y * OMDF;
    nea.z = ea.z * DECAYF + s4.z * OMDF;
    nea.w = ea.w * DECAYF + s4.w * OMDF;
    ((float4*)out_nea)[idx] = nea;
    float cs = cs_sm[k];
    float4 ne;
    ne.x = nea.x / cs; ne.y = nea.y / cs; ne.z = nea.z / cs; ne.w = nea.w / cs;
    ((float4*)out_nemb)[idx] = ne;
}

extern "C" void kernel_launch(void* const* d_in, const int* in_sizes, int n_in,
                              void* d_out, int out_size, void* d_ws, size_t ws_size,
                              hipStream_t stream) {
    const float* z            = (const float*)d_in[0];   // [N, 256]
    const float* emb          = (const float*)d_in[1];   // [1024, 256]
    const float* cluster_size = (const float*)d_in[2];   // [1024]
    const float* embed_avg    = (const float*)d_in[3];   // [1024, 256]

    const int ND = in_sizes[0];       // N*D = 16777216
    const int KD = in_sizes[1];       // K*D = 262144
    const int K  = in_sizes[2];       // 1024
    const int N  = ND / DDIM;         // 65536

    float* out       = (float*)d_out;
    float* out_zq    = out;
    float* out_loss  = out + (size_t)ND;
    float* out_codes = out + (size_t)ND + 1;
    float* out_nemb  = out + (size_t)ND + 1 + N;
    float* out_ncs   = out_nemb + (size_t)KD;
    float* out_nea   = out_ncs + (size_t)K;

    float* ws        = (float*)d_ws;
    float* loss_acc  = ws;                 // [1]
    float* counts    = ws + 1;             // [K]
    float* cs_sm     = counts + K;         // [K]
    float* esq_g     = cs_sm + K;          // [K]
    float* zsq_g     = esq_g + K;          // [N]
    float* embed_sum = zsq_g + N;          // [K*D]

    size_t base_floats = (size_t)1 + 3 * (size_t)K + (size_t)N + (size_t)KD;
    size_t f16_off = (base_floats * sizeof(float) + 255) & ~(size_t)255;
    size_t zbytes  = (size_t)N * 512 * sizeof(f16);      // 64 MB
    size_t ebytes  = (size_t)K * 512 * sizeof(f16);      // 1 MB
    bool mfma_ok   = ws_size >= f16_off + zbytes + ebytes;

    hipMemsetAsync(loss_acc, 0, sizeof(float), stream);
    if (mfma_ok) {
        static bool attr_done = false;
        if (!attr_done) {
            hipFuncSetAttribute((const void*)vq_main_mfma,
                                hipFuncAttributeMaxDynamicSharedMemorySize,
                                SMEM_BYTES);
            attr_done = true;
        }
        f16* zhl = (f16*)((char*)d_ws + f16_off);
        f16* ehl = (f16*)((char*)d_ws + f16_off + zbytes);
        vq_prep<<<(N * 32) / 256, 256, 0, stream>>>(z, zhl, zsq_g);
        vq_prep<<<(K * 32) / 256, 256, 0, stream>>>(emb, ehl, esq_g);
        vq_main_mfma<<<N / BMR, 512, SMEM_BYTES, stream>>>(
            z, emb, zhl, ehl, esq_g, zsq_g, out_zq, out_codes, loss_acc);
    } else {
        vq_esq<<<K / 256, 256, 0, stream>>>(emb, esq_g);
        vq_main_f32<<<N / BM, 256, 0, stream>>>(z, emb, esq_g,
                                                out_zq, out_codes, loss_acc);
    }
    vq_scatter<<<K, 256, 0, stream>>>(z, out_codes, embed_sum, counts);
    vq_finalize<<<1, K, 0, stream>>>(cluster_size, counts, loss_acc,
                                     out_ncs, out_loss, cs_sm, 1.0f / (float)ND);
    vq_embed<<<KD / 1024, 256, 0, stream>>>(embed_avg, embed_sum, cs_sm,
                                            out_nea, out_nemb);
}